// Round 1
// baseline (725.919 us; speedup 1.0000x reference)
//
#include <hip/hip_runtime.h>
#include <math.h>

#define NEG_SLOPE 0.2f

// ---- float <-> orderable-uint (for atomicMax on float, incl. negatives) ----
__device__ __forceinline__ unsigned f2ord(float f) {
    unsigned u = __float_as_uint(f);
    return (u & 0x80000000u) ? ~u : (u | 0x80000000u);
}
__device__ __forceinline__ float ord2f(unsigned o) {
    unsigned u = (o & 0x80000000u) ? (o & 0x7FFFFFFFu) : ~o;
    return __uint_as_float(u);
}

// K1: w_dst[d] = sum_h W_dst[d,h] * a_dst[h]   (1 block, 128 threads)
__global__ void k_wdst(const float* __restrict__ Wd, const float* __restrict__ ad,
                       float* __restrict__ wdst) {
    int d = threadIdx.x;
    float s = 0.f;
    #pragma unroll 8
    for (int h = 0; h < 128; ++h) s += Wd[d * 128 + h] * ad[h];
    wdst[d] = s;
}

// K2: out[row] = dot(X[row, 0:128], v)   — one wave per row, float2 per lane
__global__ void k_rowdot(const float* __restrict__ X, const float* __restrict__ v,
                         float* __restrict__ out, int n) {
    int wave = (int)((blockIdx.x * blockDim.x + threadIdx.x) >> 6);
    int lane = threadIdx.x & 63;
    if (wave >= n) return;
    const float2* x2 = (const float2*)(X + (size_t)wave * 128);
    const float2* v2 = (const float2*)v;
    float2 a = x2[lane], b = v2[lane];
    float p = a.x * b.x + a.y * b.y;
    #pragma unroll
    for (int off = 32; off; off >>= 1) p += __shfl_xor(p, off);
    if (lane == 0) out[wave] = p;
}

// K3: H = X @ W  (X: nrows x 128, W: 128 x 128).  32 rows/block, X tile in LDS,
// W read through L1/L2 (64 KB, hot after first block).
__global__ __launch_bounds__(256) void k_hsrc(const float* __restrict__ X,
                                              const float* __restrict__ W,
                                              float* __restrict__ H, int nrows) {
    __shared__ float Xs[32 * 128];
    int t = threadIdx.x;
    int row0 = blockIdx.x * 32;
    #pragma unroll
    for (int i = 0; i < 16; ++i) {
        int idx = t + i * 256;
        int r = row0 + (idx >> 7);
        Xs[idx] = (r < nrows) ? X[(size_t)row0 * 128 + idx] : 0.f;
    }
    __syncthreads();
    int c = t & 127, rh = t >> 7;
    float acc[16];
    #pragma unroll
    for (int j = 0; j < 16; ++j) acc[j] = 0.f;
    #pragma unroll 4
    for (int d = 0; d < 128; ++d) {
        float w = W[d * 128 + c];
        #pragma unroll
        for (int j = 0; j < 16; ++j) acc[j] += Xs[(rh * 16 + j) * 128 + d] * w;
    }
    #pragma unroll
    for (int j = 0; j < 16; ++j) {
        int r = row0 + rh * 16 + j;
        if (r < nrows) H[(size_t)r * 128 + c] = acc[j];
    }
}

// K5: per-edge attention logit + segment max (atomicMax on ordered uint)
__global__ void k_edge_logit(const int* __restrict__ src, const int* __restrict__ dst,
                             const float* __restrict__ ssrc, const float* __restrict__ sdst,
                             float* __restrict__ earr, unsigned* __restrict__ mord, int E) {
    int i = blockIdx.x * blockDim.x + threadIdx.x;
    if (i >= E) return;
    int s = src[i], d = dst[i];
    float e = ssrc[s] + sdst[d];
    e = e > 0.f ? e : NEG_SLOPE * e;
    earr[i] = e;
    atomicMax(&mord[d], f2ord(e));
}

// K6: per-edge: ex = exp(e - m[dst]); denom[dst] += ex; acc[dst,:] += ex*H[src,:]
// one wave per edge, float2 per lane -> 128 f32 atomics + 1 denom atomic
__global__ void k_edge_accum(const int* __restrict__ src, const int* __restrict__ dst,
                             const float* __restrict__ earr, const unsigned* __restrict__ mord,
                             const float* __restrict__ H, float* __restrict__ denom,
                             float* __restrict__ acc, int E) {
    int gw = (int)((blockIdx.x * blockDim.x + threadIdx.x) >> 6);
    int lane = threadIdx.x & 63;
    if (gw >= E) return;
    int s = src[gw], d = dst[gw];
    float m = ord2f(mord[d]);
    float ex = expf(earr[gw] - m);
    if (lane == 0) atomicAdd(denom + d, ex);
    const float2* h2 = (const float2*)(H + (size_t)s * 128);
    float2 v = h2[lane];
    float* a = acc + (size_t)d * 128 + lane * 2;
    atomicAdd(a, ex * v.x);
    atomicAdd(a + 1, ex * v.y);
}

// K7: out[row,:] = relu(acc[row,:]/denom[row] + b_al) @ W_lin + b_lin
// 16 rows/block (4 waves x 4 rows), W_lin staged in LDS (32 KB)
__global__ __launch_bounds__(256) void k_final(const float* __restrict__ acc,
                                               const float* __restrict__ denom,
                                               const float* __restrict__ b_al,
                                               const float* __restrict__ Wlin,
                                               const float* __restrict__ b_lin,
                                               float* __restrict__ out, int n) {
    __shared__ float Wl[128 * 64];
    __shared__ float gs[4][128];
    int t = threadIdx.x;
    #pragma unroll
    for (int i = 0; i < 32; ++i) Wl[t + i * 256] = Wlin[t + i * 256];
    int wave = t >> 6, lane = t & 63;
    float blin = b_lin[lane];
    __syncthreads();
    int row0 = blockIdx.x * 16;
    for (int r = 0; r < 4; ++r) {
        int row = row0 + wave * 4 + r;
        bool ok = row < n;
        if (ok) {
            float dn = denom[row];
            float inv = dn > 0.f ? 1.f / dn : 0.f;
            #pragma unroll
            for (int half = 0; half < 2; ++half) {
                int k = lane + half * 64;
                float g = acc[(size_t)row * 128 + k] * inv + b_al[k];
                gs[wave][k] = g > 0.f ? g : 0.f;
            }
        }
        __syncthreads();
        if (ok) {
            float o = blin;
            #pragma unroll 8
            for (int k = 0; k < 128; ++k) o += gs[wave][k] * Wl[k * 64 + lane];
            out[(size_t)row * 64 + lane] = o;
        }
        __syncthreads();
    }
}

extern "C" void kernel_launch(void* const* d_in, const int* in_sizes, int n_in,
                              void* d_out, int out_size, void* d_ws, size_t ws_size,
                              hipStream_t stream) {
    const float* x_label = (const float*)d_in[0];
    const float* x_attr  = (const float*)d_in[1];
    const float* W_src_al = (const float*)d_in[7];
    const float* W_dst_al = (const float*)d_in[8];
    const float* a_src_al = (const float*)d_in[9];
    const float* a_dst_al = (const float*)d_in[10];
    const float* b_al     = (const float*)d_in[11];
    const float* W_lin    = (const float*)d_in[12];
    const float* b_lin    = (const float*)d_in[13];
    const int* edge_src = (const int*)d_in[16];
    const int* edge_dst = (const int*)d_in[17];

    const int D = 128;
    const int N_L = in_sizes[0] / D;
    const int N_A = in_sizes[1] / D;
    const int E   = in_sizes[16];

    // workspace layout (floats)
    float* ws = (float*)d_ws;
    float*    acc   = ws;                                   // N_L*128
    float*    h_src = acc + (size_t)N_L * 128;              // N_A*128
    float*    s_src = h_src + (size_t)N_A * 128;            // N_A
    float*    s_dst = s_src + N_A;                          // N_L
    float*    wdst  = s_dst + N_L;                          // 128
    float*    earr  = wdst + 128;                           // E
    unsigned* mord  = (unsigned*)(earr + E);                // N_L
    float*    denom = (float*)(mord + N_L);                 // N_L
    float*    out   = (float*)d_out;

    // zero-init accumulators (mord=0 encodes "less than any float")
    hipMemsetAsync(acc,   0, (size_t)N_L * 128 * sizeof(float), stream);
    hipMemsetAsync(mord,  0, (size_t)N_L * sizeof(unsigned),    stream);
    hipMemsetAsync(denom, 0, (size_t)N_L * sizeof(float),       stream);

    // K1: w_dst = W_dst_al @ a_dst_al
    k_wdst<<<1, 128, 0, stream>>>(W_dst_al, a_dst_al, wdst);
    // K2: s_dst = x_label @ w_dst
    k_rowdot<<<(N_L + 3) / 4, 256, 0, stream>>>(x_label, wdst, s_dst, N_L);
    // K3: h_src = x_attr @ W_src_al
    k_hsrc<<<(N_A + 31) / 32, 256, 0, stream>>>(x_attr, W_src_al, h_src, N_A);
    // K3b: s_src = h_src @ a_src_al
    k_rowdot<<<(N_A + 3) / 4, 256, 0, stream>>>(h_src, a_src_al, s_src, N_A);
    // K5: logits + segment max
    k_edge_logit<<<(E + 255) / 256, 256, 0, stream>>>(edge_src, edge_dst, s_src, s_dst,
                                                      earr, mord, E);
    // K6: exp + weighted scatter-sum
    k_edge_accum<<<(E + 3) / 4, 256, 0, stream>>>(edge_src, edge_dst, earr, mord,
                                                  h_src, denom, acc, E);
    // K7: epilogue GEMM
    k_final<<<(N_L + 15) / 16, 256, 0, stream>>>(acc, denom, b_al, W_lin, b_lin, out, N_L);
}

// Round 2
// 423.061 us; speedup vs baseline: 1.7159x; 1.7159x over previous
//
#include <hip/hip_runtime.h>
#include <math.h>

#define NEG_SLOPE 0.2f

// K1: w_dst[d] = sum_h W_dst[d,h] * a_dst[h]   (1 block, 128 threads)
__global__ void k_wdst(const float* __restrict__ Wd, const float* __restrict__ ad,
                       float* __restrict__ wdst) {
    int d = threadIdx.x;
    float s = 0.f;
    #pragma unroll 8
    for (int h = 0; h < 128; ++h) s += Wd[d * 128 + h] * ad[h];
    wdst[d] = s;
}

// K2: out[row] = dot(X[row, 0:128], v)   — one wave per row, float2 per lane
__global__ void k_rowdot(const float* __restrict__ X, const float* __restrict__ v,
                         float* __restrict__ out, int n) {
    int wave = (int)((blockIdx.x * blockDim.x + threadIdx.x) >> 6);
    int lane = threadIdx.x & 63;
    if (wave >= n) return;
    const float2* x2 = (const float2*)(X + (size_t)wave * 128);
    const float2* v2 = (const float2*)v;
    float2 a = x2[lane], b = v2[lane];
    float p = a.x * b.x + a.y * b.y;
    #pragma unroll
    for (int off = 32; off; off >>= 1) p += __shfl_xor(p, off);
    if (lane == 0) out[wave] = p;
}

// K3: H = X @ W  (X: nrows x 128, W: 128 x 128).  32 rows/block, X tile in LDS.
__global__ __launch_bounds__(256) void k_hsrc(const float* __restrict__ X,
                                              const float* __restrict__ W,
                                              float* __restrict__ H, int nrows) {
    __shared__ float Xs[32 * 128];
    int t = threadIdx.x;
    int row0 = blockIdx.x * 32;
    #pragma unroll
    for (int i = 0; i < 16; ++i) {
        int idx = t + i * 256;
        int r = row0 + (idx >> 7);
        Xs[idx] = (r < nrows) ? X[(size_t)row0 * 128 + idx] : 0.f;
    }
    __syncthreads();
    int c = t & 127, rh = t >> 7;
    float acc[16];
    #pragma unroll
    for (int j = 0; j < 16; ++j) acc[j] = 0.f;
    #pragma unroll 4
    for (int d = 0; d < 128; ++d) {
        float w = W[d * 128 + c];
        #pragma unroll
        for (int j = 0; j < 16; ++j) acc[j] += Xs[(rh * 16 + j) * 128 + d] * w;
    }
    #pragma unroll
    for (int j = 0; j < 16; ++j) {
        int r = row0 + rh * 16 + j;
        if (r < nrows) H[(size_t)r * 128 + c] = acc[j];
    }
}

// K4a: degree histogram of dst
__global__ void k_deg(const int* __restrict__ dst, int* __restrict__ deg, int E) {
    int i = blockIdx.x * blockDim.x + threadIdx.x;
    if (i < E) atomicAdd(&deg[dst[i]], 1);
}

// K4b: per-1024-chunk block sums
__global__ __launch_bounds__(256) void k_scanA(const int* __restrict__ deg,
                                               int* __restrict__ bsum, int n) {
    __shared__ int sd[256];
    int t = threadIdx.x;
    int base = blockIdx.x * 1024 + t * 4;
    int s = 0;
    #pragma unroll
    for (int i = 0; i < 4; ++i) if (base + i < n) s += deg[base + i];
    sd[t] = s;
    __syncthreads();
    for (int off = 128; off; off >>= 1) {
        if (t < off) sd[t] += sd[t + off];
        __syncthreads();
    }
    if (t == 0) bsum[blockIdx.x] = sd[0];
}

// K4c: exclusive scan of block sums (nb ~ 98, serial in one thread is fine)
__global__ void k_scanB(int* __restrict__ bsum, int nb, int* __restrict__ rowptr, int n, int E) {
    if (threadIdx.x == 0) {
        int run = 0;
        for (int i = 0; i < nb; ++i) { int v = bsum[i]; bsum[i] = run; run += v; }
        rowptr[n] = E;
    }
}

// K4d: write exclusive prefix per element
__global__ __launch_bounds__(256) void k_scanC(const int* __restrict__ deg,
                                               const int* __restrict__ bsum,
                                               int* __restrict__ rowptr, int n) {
    __shared__ int ss[256];
    int t = threadIdx.x;
    int base = blockIdx.x * 1024 + t * 4;
    int d[4]; int tsum = 0;
    #pragma unroll
    for (int i = 0; i < 4; ++i) { d[i] = (base + i < n) ? deg[base + i] : 0; tsum += d[i]; }
    ss[t] = tsum;
    __syncthreads();
    for (int off = 1; off < 256; off <<= 1) {
        int v = (t >= off) ? ss[t - off] : 0;
        __syncthreads();
        ss[t] += v;
        __syncthreads();
    }
    int excl = ss[t] - tsum + bsum[blockIdx.x];
    #pragma unroll
    for (int i = 0; i < 4; ++i) {
        if (base + i < n) rowptr[base + i] = excl;
        excl += d[i];
    }
}

// K5: compute e, place edge into CSR slot
__global__ void k_scatter(const int* __restrict__ src, const int* __restrict__ dst,
                          const float* __restrict__ ssrc, const float* __restrict__ sdst,
                          const int* __restrict__ rowptr, int* __restrict__ cursor,
                          int* __restrict__ csr_src, float* __restrict__ csr_e, int E) {
    int i = blockIdx.x * blockDim.x + threadIdx.x;
    if (i >= E) return;
    int s = src[i], d = dst[i];
    float e = ssrc[s] + sdst[d];
    e = e > 0.f ? e : NEG_SLOPE * e;
    int pos = rowptr[d] + atomicAdd(&cursor[d], 1);
    csr_src[pos] = s;
    csr_e[pos] = e;
}

// K6: one wave per dst row (2 rows/wave): segment softmax + weighted gather-sum
// in registers, fused epilogue: relu(acc/denom + b_al) @ W_lin + b_lin.
__global__ __launch_bounds__(256) void k_gat_row(
    const int* __restrict__ rowptr, const int* __restrict__ csr_src,
    const float* __restrict__ csr_e, const float* __restrict__ H,
    const float* __restrict__ b_al, const float* __restrict__ Wlin,
    const float* __restrict__ b_lin, float* __restrict__ out, int n) {
    __shared__ float Wl[128 * 64];
    int t = threadIdx.x;
    #pragma unroll
    for (int i = 0; i < 32; ++i) Wl[t + i * 256] = Wlin[t + i * 256];
    __syncthreads();
    int wave = t >> 6, lane = t & 63;
    float blin = b_lin[lane];
    float ba0 = b_al[lane * 2], ba1 = b_al[lane * 2 + 1];
    int stride = gridDim.x * 4 * 2;
    for (int row0 = (blockIdx.x * 4 + wave) * 2; row0 < n; row0 += stride) {
        float g0[2], g1[2];  // [rr][elem]: this wave's relu'd feature pair for 2 rows
        #pragma unroll
        for (int rr = 0; rr < 2; ++rr) {
            int row = row0 + rr;
            if (row >= n) { g0[rr] = 0.f; g1[rr] = 0.f; continue; }
            int beg = rowptr[row], end = rowptr[row + 1];
            // segment max (lanes cooperate)
            float m = -INFINITY;
            for (int j = beg + lane; j < end; j += 64) m = fmaxf(m, csr_e[j]);
            #pragma unroll
            for (int off = 32; off; off >>= 1) m = fmaxf(m, __shfl_xor(m, off));
            // serial edge loop: exp + gather H[src] (float2/lane)
            float denom = 0.f, ax = 0.f, ay = 0.f;
            for (int j = beg; j < end; ++j) {
                int s = csr_src[j];
                float ex = __expf(csr_e[j] - m);
                denom += ex;
                const float2 h = ((const float2*)(H + (size_t)s * 128))[lane];
                ax += ex * h.x;
                ay += ex * h.y;
            }
            float inv = denom > 0.f ? 1.f / denom : 0.f;
            float v0 = ax * inv + ba0, v1 = ay * inv + ba1;
            g0[rr] = v0 > 0.f ? v0 : 0.f;
            g1[rr] = v1 > 0.f ? v1 : 0.f;
        }
        // epilogue: out[row,:] = g @ W_lin + b_lin, g broadcast via readlane,
        // Wl reads shared across the 2 rows
        float oA = blin, oB = blin;
        #pragma unroll 8
        for (int k2 = 0; k2 < 64; ++k2) {
            float wA = Wl[(2 * k2) * 64 + lane];
            float wB = Wl[(2 * k2 + 1) * 64 + lane];
            float gA0 = __shfl(g0[0], k2), gB0 = __shfl(g1[0], k2);
            float gA1 = __shfl(g0[1], k2), gB1 = __shfl(g1[1], k2);
            oA += gA0 * wA + gB0 * wB;
            oB += gA1 * wA + gB1 * wB;
        }
        out[(size_t)row0 * 64 + lane] = oA;
        if (row0 + 1 < n) out[(size_t)(row0 + 1) * 64 + lane] = oB;
    }
}

extern "C" void kernel_launch(void* const* d_in, const int* in_sizes, int n_in,
                              void* d_out, int out_size, void* d_ws, size_t ws_size,
                              hipStream_t stream) {
    const float* x_label  = (const float*)d_in[0];
    const float* x_attr   = (const float*)d_in[1];
    const float* W_src_al = (const float*)d_in[7];
    const float* W_dst_al = (const float*)d_in[8];
    const float* a_src_al = (const float*)d_in[9];
    const float* a_dst_al = (const float*)d_in[10];
    const float* b_al     = (const float*)d_in[11];
    const float* W_lin    = (const float*)d_in[12];
    const float* b_lin    = (const float*)d_in[13];
    const int* edge_src   = (const int*)d_in[16];
    const int* edge_dst   = (const int*)d_in[17];

    const int D = 128;
    const int N_L = in_sizes[0] / D;
    const int N_A = in_sizes[1] / D;
    const int E   = in_sizes[16];
    const int nb  = (N_L + 1023) / 1024;

    // workspace layout
    float* ws = (float*)d_ws;
    float* h_src = ws;                                  // N_A*128
    float* s_src = h_src + (size_t)N_A * 128;           // N_A
    float* s_dst = s_src + N_A;                         // N_L
    float* wdst  = s_dst + N_L;                         // 128
    int*   deg    = (int*)(wdst + 128);                 // N_L
    int*   cursor = deg + N_L;                          // N_L
    int*   rowptr = cursor + N_L;                       // N_L + 1
    int*   bsum   = rowptr + N_L + 1;                   // nb (pad to 128)
    int*   csr_src = bsum + 128;                        // E
    float* csr_e   = (float*)(csr_src + E);             // E
    float* out = (float*)d_out;

    hipMemsetAsync(deg,    0, (size_t)N_L * sizeof(int), stream);
    hipMemsetAsync(cursor, 0, (size_t)N_L * sizeof(int), stream);

    // scalar projections
    k_wdst<<<1, 128, 0, stream>>>(W_dst_al, a_dst_al, wdst);
    k_rowdot<<<(N_L + 3) / 4, 256, 0, stream>>>(x_label, wdst, s_dst, N_L);
    // h_src GEMM + its scalar projection
    k_hsrc<<<(N_A + 31) / 32, 256, 0, stream>>>(x_attr, W_src_al, h_src, N_A);
    k_rowdot<<<(N_A + 3) / 4, 256, 0, stream>>>(h_src, a_src_al, s_src, N_A);
    // CSR build
    k_deg<<<(E + 255) / 256, 256, 0, stream>>>(edge_dst, deg, E);
    k_scanA<<<nb, 256, 0, stream>>>(deg, bsum, N_L);
    k_scanB<<<1, 64, 0, stream>>>(bsum, nb, rowptr, N_L, E);
    k_scanC<<<nb, 256, 0, stream>>>(deg, bsum, rowptr, N_L);
    k_scatter<<<(E + 255) / 256, 256, 0, stream>>>(edge_src, edge_dst, s_src, s_dst,
                                                   rowptr, cursor, csr_src, csr_e, E);
    // fused per-row GAT + epilogue
    k_gat_row<<<2048, 256, 0, stream>>>(rowptr, csr_src, csr_e, h_src,
                                        b_al, W_lin, b_lin, out, N_L);
}

// Round 3
// 378.355 us; speedup vs baseline: 1.9186x; 1.1182x over previous
//
#include <hip/hip_runtime.h>
#include <math.h>

#define NEG_SLOPE 0.2f

// K1: w_dst[d] = sum_h W_dst[d,h] * a_dst[h]   (1 block, 128 threads)
__global__ void k_wdst(const float* __restrict__ Wd, const float* __restrict__ ad,
                       float* __restrict__ wdst) {
    int d = threadIdx.x;
    float s = 0.f;
    #pragma unroll 8
    for (int h = 0; h < 128; ++h) s += Wd[d * 128 + h] * ad[h];
    wdst[d] = s;
}

// K2: out[row] = dot(X[row, 0:128], v)   — one wave per row, float2 per lane
__global__ void k_rowdot(const float* __restrict__ X, const float* __restrict__ v,
                         float* __restrict__ out, int n) {
    int wave = (int)((blockIdx.x * blockDim.x + threadIdx.x) >> 6);
    int lane = threadIdx.x & 63;
    if (wave >= n) return;
    const float2* x2 = (const float2*)(X + (size_t)wave * 128);
    const float2* v2 = (const float2*)v;
    float2 a = x2[lane], b = v2[lane];
    float p = a.x * b.x + a.y * b.y;
    #pragma unroll
    for (int off = 32; off; off >>= 1) p += __shfl_xor(p, off);
    if (lane == 0) out[wave] = p;
}

// K3: H = X @ W  (X: nrows x 128, W: 128 x 128). 32 rows/block, 4x4 register
// tile per thread: per d, 4 broadcast LDS reads + 1 float4 W read (L1-hot) + 16 FMA.
__global__ __launch_bounds__(256) void k_hsrc(const float* __restrict__ X,
                                              const float* __restrict__ W,
                                              float* __restrict__ H, int nrows) {
    __shared__ float Xs[32][128];
    int t = threadIdx.x;
    int row0 = blockIdx.x * 32;
    #pragma unroll
    for (int i = 0; i < 16; ++i) {
        int idx = t + i * 256;
        int r = idx >> 7;
        Xs[r][idx & 127] = (row0 + r < nrows) ? X[(size_t)row0 * 128 + idx] : 0.f;
    }
    __syncthreads();
    int cg = t & 31, rg = t >> 5;   // cols cg*4.., rows rg*4..
    float acc[4][4];
    #pragma unroll
    for (int i = 0; i < 4; ++i)
        #pragma unroll
        for (int j = 0; j < 4; ++j) acc[i][j] = 0.f;
    const float4* W4 = (const float4*)W;
    #pragma unroll 4
    for (int d = 0; d < 128; ++d) {
        float4 wv = W4[d * 32 + cg];
        float x0 = Xs[rg * 4 + 0][d], x1 = Xs[rg * 4 + 1][d];
        float x2 = Xs[rg * 4 + 2][d], x3 = Xs[rg * 4 + 3][d];
        acc[0][0] += x0 * wv.x; acc[0][1] += x0 * wv.y; acc[0][2] += x0 * wv.z; acc[0][3] += x0 * wv.w;
        acc[1][0] += x1 * wv.x; acc[1][1] += x1 * wv.y; acc[1][2] += x1 * wv.z; acc[1][3] += x1 * wv.w;
        acc[2][0] += x2 * wv.x; acc[2][1] += x2 * wv.y; acc[2][2] += x2 * wv.z; acc[2][3] += x2 * wv.w;
        acc[3][0] += x3 * wv.x; acc[3][1] += x3 * wv.y; acc[3][2] += x3 * wv.z; acc[3][3] += x3 * wv.w;
    }
    #pragma unroll
    for (int i = 0; i < 4; ++i) {
        int gr = row0 + rg * 4 + i;
        if (gr < nrows) {
            float4 o = make_float4(acc[i][0], acc[i][1], acc[i][2], acc[i][3]);
            *(float4*)&H[(size_t)gr * 128 + cg * 4] = o;
        }
    }
}

// K4a: degree histogram of dst
__global__ void k_deg(const int* __restrict__ dst, int* __restrict__ deg, int E) {
    int i = blockIdx.x * blockDim.x + threadIdx.x;
    if (i < E) atomicAdd(&deg[dst[i]], 1);
}

// K4b: per-1024-chunk block sums
__global__ __launch_bounds__(256) void k_scanA(const int* __restrict__ deg,
                                               int* __restrict__ bsum, int n) {
    __shared__ int sd[256];
    int t = threadIdx.x;
    int base = blockIdx.x * 1024 + t * 4;
    int s = 0;
    #pragma unroll
    for (int i = 0; i < 4; ++i) if (base + i < n) s += deg[base + i];
    sd[t] = s;
    __syncthreads();
    for (int off = 128; off; off >>= 1) {
        if (t < off) sd[t] += sd[t + off];
        __syncthreads();
    }
    if (t == 0) bsum[blockIdx.x] = sd[0];
}

// K4c: parallel exclusive scan of block sums (nb <= 128; serial fallback else)
__global__ __launch_bounds__(128) void k_scanB(int* __restrict__ bsum, int nb,
                                               int* __restrict__ rowptr, int n, int E) {
    __shared__ int ss[128];
    int t = threadIdx.x;
    if (nb <= 128) {
        int v = (t < nb) ? bsum[t] : 0;
        ss[t] = v;
        __syncthreads();
        for (int off = 1; off < 128; off <<= 1) {
            int u = (t >= off) ? ss[t - off] : 0;
            __syncthreads();
            ss[t] += u;
            __syncthreads();
        }
        if (t < nb) bsum[t] = ss[t] - v;   // exclusive
    } else if (t == 0) {
        int run = 0;
        for (int i = 0; i < nb; ++i) { int v = bsum[i]; bsum[i] = run; run += v; }
    }
    if (t == 0) rowptr[n] = E;
}

// K4d: write exclusive prefix per element
__global__ __launch_bounds__(256) void k_scanC(const int* __restrict__ deg,
                                               const int* __restrict__ bsum,
                                               int* __restrict__ rowptr, int n) {
    __shared__ int ss[256];
    int t = threadIdx.x;
    int base = blockIdx.x * 1024 + t * 4;
    int d[4]; int tsum = 0;
    #pragma unroll
    for (int i = 0; i < 4; ++i) { d[i] = (base + i < n) ? deg[base + i] : 0; tsum += d[i]; }
    ss[t] = tsum;
    __syncthreads();
    for (int off = 1; off < 256; off <<= 1) {
        int v = (t >= off) ? ss[t - off] : 0;
        __syncthreads();
        ss[t] += v;
        __syncthreads();
    }
    int excl = ss[t] - tsum + bsum[blockIdx.x];
    #pragma unroll
    for (int i = 0; i < 4; ++i) {
        if (base + i < n) rowptr[base + i] = excl;
        excl += d[i];
    }
}

// K5: compute e, place edge into CSR slot
__global__ void k_scatter(const int* __restrict__ src, const int* __restrict__ dst,
                          const float* __restrict__ ssrc, const float* __restrict__ sdst,
                          const int* __restrict__ rowptr, int* __restrict__ cursor,
                          int* __restrict__ csr_src, float* __restrict__ csr_e, int E) {
    int i = blockIdx.x * blockDim.x + threadIdx.x;
    if (i >= E) return;
    int s = src[i], d = dst[i];
    float e = ssrc[s] + sdst[d];
    e = e > 0.f ? e : NEG_SLOPE * e;
    int pos = rowptr[d] + atomicAdd(&cursor[d], 1);
    csr_src[pos] = s;
    csr_e[pos] = e;
}

// K6: one wave per dst row (2 rows/wave): segment softmax + weighted gather-sum,
// batch-4 prefetched gathers for MLP; fused epilogue relu(./denom + b) @ W_lin + b_lin.
// No LDS: W_lin read through L1 (32 KB, identical across waves, hot).
__global__ __launch_bounds__(256) void k_gat_row(
    const int* __restrict__ rowptr, const int* __restrict__ csr_src,
    const float* __restrict__ csr_e, const float* __restrict__ H,
    const float* __restrict__ b_al, const float* __restrict__ Wlin,
    const float* __restrict__ b_lin, float* __restrict__ out, int n) {
    int t = threadIdx.x;
    int wave = t >> 6, lane = t & 63;
    float blin = b_lin[lane];
    float ba0 = b_al[lane * 2], ba1 = b_al[lane * 2 + 1];
    const float2* H2 = (const float2*)H;
    int stride = gridDim.x * 4 * 2;
    for (int row0 = (blockIdx.x * 4 + wave) * 2; row0 < n; row0 += stride) {
        float g0[2], g1[2];
        #pragma unroll
        for (int rr = 0; rr < 2; ++rr) {
            int row = row0 + rr;
            if (row >= n) { g0[rr] = 0.f; g1[rr] = 0.f; continue; }
            int beg = rowptr[row], end = rowptr[row + 1];
            // segment max (lanes cooperate)
            float m = -INFINITY;
            for (int j = beg + lane; j < end; j += 64) m = fmaxf(m, csr_e[j]);
            #pragma unroll
            for (int off = 32; off; off >>= 1) m = fmaxf(m, __shfl_xor(m, off));
            float denom = 0.f, ax = 0.f, ay = 0.f;
            int j = beg;
            // batch-4: 8 index/logit loads, then 4 independent H gathers in flight
            for (; j + 4 <= end; j += 4) {
                int s0 = csr_src[j], s1 = csr_src[j + 1];
                int s2 = csr_src[j + 2], s3 = csr_src[j + 3];
                float e0 = csr_e[j], e1 = csr_e[j + 1];
                float e2 = csr_e[j + 2], e3 = csr_e[j + 3];
                float2 h0 = H2[(size_t)s0 * 64 + lane];
                float2 h1 = H2[(size_t)s1 * 64 + lane];
                float2 h2 = H2[(size_t)s2 * 64 + lane];
                float2 h3 = H2[(size_t)s3 * 64 + lane];
                float x0 = __expf(e0 - m), x1 = __expf(e1 - m);
                float x2 = __expf(e2 - m), x3 = __expf(e3 - m);
                denom += (x0 + x1) + (x2 + x3);
                ax += x0 * h0.x + x1 * h1.x + x2 * h2.x + x3 * h3.x;
                ay += x0 * h0.y + x1 * h1.y + x2 * h2.y + x3 * h3.y;
            }
            for (; j < end; ++j) {
                int s = csr_src[j];
                float ex = __expf(csr_e[j] - m);
                float2 h = H2[(size_t)s * 64 + lane];
                denom += ex;
                ax += ex * h.x;
                ay += ex * h.y;
            }
            float inv = denom > 0.f ? 1.f / denom : 0.f;
            float v0 = ax * inv + ba0, v1 = ay * inv + ba1;
            g0[rr] = fmaxf(v0, 0.f);
            g1[rr] = fmaxf(v1, 0.f);
        }
        // epilogue: out[row,:] = g @ W_lin + b_lin (g broadcast via shfl)
        float oA = blin, oB = blin;
        #pragma unroll 8
        for (int k2 = 0; k2 < 64; ++k2) {
            float wA = Wlin[(2 * k2) * 64 + lane];
            float wB = Wlin[(2 * k2 + 1) * 64 + lane];
            float gA0 = __shfl(g0[0], k2), gB0 = __shfl(g1[0], k2);
            float gA1 = __shfl(g0[1], k2), gB1 = __shfl(g1[1], k2);
            oA += gA0 * wA + gB0 * wB;
            oB += gA1 * wA + gB1 * wB;
        }
        out[(size_t)row0 * 64 + lane] = oA;
        if (row0 + 1 < n) out[(size_t)(row0 + 1) * 64 + lane] = oB;
    }
}

extern "C" void kernel_launch(void* const* d_in, const int* in_sizes, int n_in,
                              void* d_out, int out_size, void* d_ws, size_t ws_size,
                              hipStream_t stream) {
    const float* x_label  = (const float*)d_in[0];
    const float* x_attr   = (const float*)d_in[1];
    const float* W_src_al = (const float*)d_in[7];
    const float* W_dst_al = (const float*)d_in[8];
    const float* a_src_al = (const float*)d_in[9];
    const float* a_dst_al = (const float*)d_in[10];
    const float* b_al     = (const float*)d_in[11];
    const float* W_lin    = (const float*)d_in[12];
    const float* b_lin    = (const float*)d_in[13];
    const int* edge_src   = (const int*)d_in[16];
    const int* edge_dst   = (const int*)d_in[17];

    const int D = 128;
    const int N_L = in_sizes[0] / D;
    const int N_A = in_sizes[1] / D;
    const int E   = in_sizes[16];
    const int nb  = (N_L + 1023) / 1024;

    // workspace layout
    float* ws = (float*)d_ws;
    float* h_src = ws;                                  // N_A*128
    float* s_src = h_src + (size_t)N_A * 128;           // N_A
    float* s_dst = s_src + N_A;                         // N_L
    float* wdst  = s_dst + N_L;                         // 128
    int*   deg    = (int*)(wdst + 128);                 // N_L
    int*   cursor = deg + N_L;                          // N_L
    int*   rowptr = cursor + N_L;                       // N_L + 1
    int*   bsum   = rowptr + N_L + 1;                   // nb (pad to 128)
    int*   csr_src = bsum + 128;                        // E
    float* csr_e   = (float*)(csr_src + E);             // E
    float* out = (float*)d_out;

    hipMemsetAsync(deg,    0, (size_t)N_L * sizeof(int), stream);
    hipMemsetAsync(cursor, 0, (size_t)N_L * sizeof(int), stream);

    // scalar projections
    k_wdst<<<1, 128, 0, stream>>>(W_dst_al, a_dst_al, wdst);
    k_rowdot<<<(N_L + 3) / 4, 256, 0, stream>>>(x_label, wdst, s_dst, N_L);
    // h_src GEMM + its scalar projection
    k_hsrc<<<(N_A + 31) / 32, 256, 0, stream>>>(x_attr, W_src_al, h_src, N_A);
    k_rowdot<<<(N_A + 3) / 4, 256, 0, stream>>>(h_src, a_src_al, s_src, N_A);
    // CSR build
    k_deg<<<(E + 255) / 256, 256, 0, stream>>>(edge_dst, deg, E);
    k_scanA<<<nb, 256, 0, stream>>>(deg, bsum, N_L);
    k_scanB<<<1, 128, 0, stream>>>(bsum, nb, rowptr, N_L, E);
    k_scanC<<<nb, 256, 0, stream>>>(deg, bsum, rowptr, N_L);
    k_scatter<<<(E + 255) / 256, 256, 0, stream>>>(edge_src, edge_dst, s_src, s_dst,
                                                   rowptr, cursor, csr_src, csr_e, E);
    // fused per-row GAT + epilogue
    k_gat_row<<<2048, 256, 0, stream>>>(rowptr, csr_src, csr_e, h_src,
                                        b_al, W_lin, b_lin, out, N_L);
}

// Round 4
// 351.747 us; speedup vs baseline: 2.0638x; 1.0756x over previous
//
#include <hip/hip_runtime.h>
#include <math.h>

#define NEG_SLOPE 0.2f

// K1: w_dst[d] = sum_h W_dst[d,h] * a_dst[h]   (1 block, 128 threads)
__global__ void k_wdst(const float* __restrict__ Wd, const float* __restrict__ ad,
                       float* __restrict__ wdst) {
    int d = threadIdx.x;
    float s = 0.f;
    #pragma unroll 8
    for (int h = 0; h < 128; ++h) s += Wd[d * 128 + h] * ad[h];
    wdst[d] = s;
}

// K2: out[row] = dot(X[row,0:128], v). 2 rows per wave, float4/lane, coalesced.
__global__ void k_rowdot(const float* __restrict__ X, const float* __restrict__ v,
                         float* __restrict__ out, int n) {
    int gw = (int)((blockIdx.x * blockDim.x + threadIdx.x) >> 6);  // wave id
    int lane = threadIdx.x & 63;
    int half = lane >> 5, li = lane & 31;
    int row = gw * 2 + half;
    if (row >= n) return;
    const float4* X4 = (const float4*)X;
    const float4* V4 = (const float4*)v;
    float4 x = X4[(size_t)row * 32 + li];
    float4 b = V4[li];
    float p = x.x * b.x + x.y * b.y + x.z * b.z + x.w * b.w;
    #pragma unroll
    for (int off = 16; off; off >>= 1) p += __shfl_xor(p, off);
    if (li == 0) out[row] = p;
}

// K3: H = X @ W  (X: nrows x 128, W: 128 x 128). 32 rows/block, 4x4 register tile.
__global__ __launch_bounds__(256) void k_hsrc(const float* __restrict__ X,
                                              const float* __restrict__ W,
                                              float* __restrict__ H, int nrows) {
    __shared__ float Xs[32][128];
    int t = threadIdx.x;
    int row0 = blockIdx.x * 32;
    #pragma unroll
    for (int i = 0; i < 16; ++i) {
        int idx = t + i * 256;
        int r = idx >> 7;
        Xs[r][idx & 127] = (row0 + r < nrows) ? X[(size_t)row0 * 128 + idx] : 0.f;
    }
    __syncthreads();
    int cg = t & 31, rg = t >> 5;
    float acc[4][4];
    #pragma unroll
    for (int i = 0; i < 4; ++i)
        #pragma unroll
        for (int j = 0; j < 4; ++j) acc[i][j] = 0.f;
    const float4* W4 = (const float4*)W;
    #pragma unroll 4
    for (int d = 0; d < 128; ++d) {
        float4 wv = W4[d * 32 + cg];
        float x0 = Xs[rg * 4 + 0][d], x1 = Xs[rg * 4 + 1][d];
        float x2 = Xs[rg * 4 + 2][d], x3 = Xs[rg * 4 + 3][d];
        acc[0][0] += x0 * wv.x; acc[0][1] += x0 * wv.y; acc[0][2] += x0 * wv.z; acc[0][3] += x0 * wv.w;
        acc[1][0] += x1 * wv.x; acc[1][1] += x1 * wv.y; acc[1][2] += x1 * wv.z; acc[1][3] += x1 * wv.w;
        acc[2][0] += x2 * wv.x; acc[2][1] += x2 * wv.y; acc[2][2] += x2 * wv.z; acc[2][3] += x2 * wv.w;
        acc[3][0] += x3 * wv.x; acc[3][1] += x3 * wv.y; acc[3][2] += x3 * wv.z; acc[3][3] += x3 * wv.w;
    }
    #pragma unroll
    for (int i = 0; i < 4; ++i) {
        int gr = row0 + rg * 4 + i;
        if (gr < nrows) {
            float4 o = make_float4(acc[i][0], acc[i][1], acc[i][2], acc[i][3]);
            *(float4*)&H[(size_t)gr * 128 + cg * 4] = o;
        }
    }
}

// K4a: degree histogram of dst
__global__ void k_deg(const int* __restrict__ dst, int* __restrict__ deg, int E) {
    int i = blockIdx.x * blockDim.x + threadIdx.x;
    if (i < E) atomicAdd(&deg[dst[i]], 1);
}

// K4b: per-1024-chunk block sums
__global__ __launch_bounds__(256) void k_scanA(const int* __restrict__ deg,
                                               int* __restrict__ bsum, int n) {
    __shared__ int sd[256];
    int t = threadIdx.x;
    int base = blockIdx.x * 1024 + t * 4;
    int s = 0;
    #pragma unroll
    for (int i = 0; i < 4; ++i) if (base + i < n) s += deg[base + i];
    sd[t] = s;
    __syncthreads();
    for (int off = 128; off; off >>= 1) {
        if (t < off) sd[t] += sd[t + off];
        __syncthreads();
    }
    if (t == 0) bsum[blockIdx.x] = sd[0];
}

// K4c: parallel exclusive scan of block sums
__global__ __launch_bounds__(128) void k_scanB(int* __restrict__ bsum, int nb,
                                               int* __restrict__ rowptr, int n, int E) {
    __shared__ int ss[128];
    int t = threadIdx.x;
    if (nb <= 128) {
        int v = (t < nb) ? bsum[t] : 0;
        ss[t] = v;
        __syncthreads();
        for (int off = 1; off < 128; off <<= 1) {
            int u = (t >= off) ? ss[t - off] : 0;
            __syncthreads();
            ss[t] += u;
            __syncthreads();
        }
        if (t < nb) bsum[t] = ss[t] - v;
    } else if (t == 0) {
        int run = 0;
        for (int i = 0; i < nb; ++i) { int v = bsum[i]; bsum[i] = run; run += v; }
    }
    if (t == 0) rowptr[n] = E;
}

// K4d: write exclusive prefix per element
__global__ __launch_bounds__(256) void k_scanC(const int* __restrict__ deg,
                                               const int* __restrict__ bsum,
                                               int* __restrict__ rowptr, int n) {
    __shared__ int ss[256];
    int t = threadIdx.x;
    int base = blockIdx.x * 1024 + t * 4;
    int d[4]; int tsum = 0;
    #pragma unroll
    for (int i = 0; i < 4; ++i) { d[i] = (base + i < n) ? deg[base + i] : 0; tsum += d[i]; }
    ss[t] = tsum;
    __syncthreads();
    for (int off = 1; off < 256; off <<= 1) {
        int v = (t >= off) ? ss[t - off] : 0;
        __syncthreads();
        ss[t] += v;
        __syncthreads();
    }
    int excl = ss[t] - tsum + bsum[blockIdx.x];
    #pragma unroll
    for (int i = 0; i < 4; ++i) {
        if (base + i < n) rowptr[base + i] = excl;
        excl += d[i];
    }
}

// K5: compute ex = exp(leaky(e)) (max-free softmax numerator), pack (src, ex)
__global__ void k_scatter(const int* __restrict__ src, const int* __restrict__ dst,
                          const float* __restrict__ ssrc, const float* __restrict__ sdst,
                          const int* __restrict__ rowptr, int* __restrict__ cursor,
                          int2* __restrict__ csr_pair, int E) {
    int i = blockIdx.x * blockDim.x + threadIdx.x;
    if (i >= E) return;
    int s = src[i], d = dst[i];
    float e = ssrc[s] + sdst[d];
    e = e > 0.f ? e : NEG_SLOPE * e;
    float ex = __expf(e);
    int pos = rowptr[d] + atomicAdd(&cursor[d], 1);
    csr_pair[pos] = make_int2(s, __float_as_int(ex));
}

// K6: gather+accumulate. 4 rows per wave (16 lanes/row, float4 x2 per lane),
// batch-2 edges. Writes G[row,:] = relu(acc/denom + b_al).
__global__ __launch_bounds__(256) void k_gat(
    const int* __restrict__ rowptr, const int2* __restrict__ csr_pair,
    const float* __restrict__ H, const float* __restrict__ b_al,
    float* __restrict__ G, int n) {
    int t = threadIdx.x;
    int wave = t >> 6, lane = t & 63;
    int grp = lane >> 4, gl = lane & 15;
    int row = blockIdx.x * 16 + wave * 4 + grp;
    if (row >= n) return;
    int beg = rowptr[row], end = rowptr[row + 1];
    const float4* H4 = (const float4*)H;
    float4 aA = make_float4(0.f, 0.f, 0.f, 0.f);
    float4 aB = make_float4(0.f, 0.f, 0.f, 0.f);
    float denom = 0.f;
    int j = beg;
    for (; j + 2 <= end; j += 2) {
        int2 p0 = csr_pair[j], p1 = csr_pair[j + 1];
        float x0 = __int_as_float(p0.y), x1 = __int_as_float(p1.y);
        float4 h0a = H4[(size_t)p0.x * 32 + gl];
        float4 h0b = H4[(size_t)p0.x * 32 + 16 + gl];
        float4 h1a = H4[(size_t)p1.x * 32 + gl];
        float4 h1b = H4[(size_t)p1.x * 32 + 16 + gl];
        denom += x0 + x1;
        aA.x += x0 * h0a.x + x1 * h1a.x; aA.y += x0 * h0a.y + x1 * h1a.y;
        aA.z += x0 * h0a.z + x1 * h1a.z; aA.w += x0 * h0a.w + x1 * h1a.w;
        aB.x += x0 * h0b.x + x1 * h1b.x; aB.y += x0 * h0b.y + x1 * h1b.y;
        aB.z += x0 * h0b.z + x1 * h1b.z; aB.w += x0 * h0b.w + x1 * h1b.w;
    }
    if (j < end) {
        int2 p0 = csr_pair[j];
        float x0 = __int_as_float(p0.y);
        float4 h0a = H4[(size_t)p0.x * 32 + gl];
        float4 h0b = H4[(size_t)p0.x * 32 + 16 + gl];
        denom += x0;
        aA.x += x0 * h0a.x; aA.y += x0 * h0a.y; aA.z += x0 * h0a.z; aA.w += x0 * h0a.w;
        aB.x += x0 * h0b.x; aB.y += x0 * h0b.y; aB.z += x0 * h0b.z; aB.w += x0 * h0b.w;
    }
    float inv = denom > 0.f ? 1.f / denom : 0.f;
    const float4* B4 = (const float4*)b_al;
    float4 bA = B4[gl], bB = B4[16 + gl];
    float4 gA, gB;
    gA.x = fmaxf(aA.x * inv + bA.x, 0.f); gA.y = fmaxf(aA.y * inv + bA.y, 0.f);
    gA.z = fmaxf(aA.z * inv + bA.z, 0.f); gA.w = fmaxf(aA.w * inv + bA.w, 0.f);
    gB.x = fmaxf(aB.x * inv + bB.x, 0.f); gB.y = fmaxf(aB.y * inv + bB.y, 0.f);
    gB.z = fmaxf(aB.z * inv + bB.z, 0.f); gB.w = fmaxf(aB.w * inv + bB.w, 0.f);
    float4* G4 = (float4*)G;
    G4[(size_t)row * 32 + gl] = gA;
    G4[(size_t)row * 32 + 16 + gl] = gB;
}

// K7: out = G @ W_lin + b_lin.  W_lin in LDS; lane = output col; wave = row;
// uniform float4 reads of G row broadcast across the wave.
__global__ __launch_bounds__(256) void k_out(const float* __restrict__ G,
                                             const float* __restrict__ Wlin,
                                             const float* __restrict__ b_lin,
                                             float* __restrict__ out, int n) {
    __shared__ float Wls[128 * 64];
    int t = threadIdx.x;
    #pragma unroll
    for (int i = 0; i < 32; ++i) Wls[t + i * 256] = Wlin[t + i * 256];
    __syncthreads();
    int wave = t >> 6, lane = t & 63;
    float bl = b_lin[lane];
    const float4* G4 = (const float4*)G;
    int gw0 = blockIdx.x * 4 + wave;
    int nw = gridDim.x * 4;
    for (int row = gw0; row < n; row += nw) {
        float acc = bl;
        #pragma unroll 8
        for (int kk = 0; kk < 32; ++kk) {
            float4 g = G4[(size_t)row * 32 + kk];
            acc += g.x * Wls[(4 * kk + 0) * 64 + lane];
            acc += g.y * Wls[(4 * kk + 1) * 64 + lane];
            acc += g.z * Wls[(4 * kk + 2) * 64 + lane];
            acc += g.w * Wls[(4 * kk + 3) * 64 + lane];
        }
        out[(size_t)row * 64 + lane] = acc;
    }
}

extern "C" void kernel_launch(void* const* d_in, const int* in_sizes, int n_in,
                              void* d_out, int out_size, void* d_ws, size_t ws_size,
                              hipStream_t stream) {
    const float* x_label  = (const float*)d_in[0];
    const float* x_attr   = (const float*)d_in[1];
    const float* W_src_al = (const float*)d_in[7];
    const float* W_dst_al = (const float*)d_in[8];
    const float* a_src_al = (const float*)d_in[9];
    const float* a_dst_al = (const float*)d_in[10];
    const float* b_al     = (const float*)d_in[11];
    const float* W_lin    = (const float*)d_in[12];
    const float* b_lin    = (const float*)d_in[13];
    const int* edge_src   = (const int*)d_in[16];
    const int* edge_dst   = (const int*)d_in[17];

    const int D = 128;
    const int N_L = in_sizes[0] / D;
    const int N_A = in_sizes[1] / D;
    const int E   = in_sizes[16];
    const int nb  = (N_L + 1023) / 1024;

    // workspace layout (floats; keep csr_pair 8B-aligned: all offsets even)
    float* ws = (float*)d_ws;
    float* h_src = ws;                                  // N_A*128
    float* s_src = h_src + (size_t)N_A * 128;           // N_A
    float* s_dst = s_src + N_A;                         // N_L
    float* wdst  = s_dst + N_L;                         // 128
    int*   deg    = (int*)(wdst + 128);                 // N_L
    int*   cursor = deg + N_L;                          // N_L
    int*   rowptr = cursor + N_L;                       // N_L + 2 (pad, even)
    int*   bsum   = rowptr + N_L + 2;                   // 128
    int2*  csr_pair = (int2*)(bsum + 128);              // E (8B each)
    float* G = (float*)(csr_pair + E);                  // N_L*128
    float* out = (float*)d_out;

    hipMemsetAsync(deg,    0, (size_t)N_L * sizeof(int), stream);
    hipMemsetAsync(cursor, 0, (size_t)N_L * sizeof(int), stream);

    // scalar projections
    k_wdst<<<1, 128, 0, stream>>>(W_dst_al, a_dst_al, wdst);
    k_rowdot<<<(N_L + 7) / 8, 256, 0, stream>>>(x_label, wdst, s_dst, N_L);
    // h_src GEMM + its scalar projection
    k_hsrc<<<(N_A + 31) / 32, 256, 0, stream>>>(x_attr, W_src_al, h_src, N_A);
    k_rowdot<<<(N_A + 7) / 8, 256, 0, stream>>>(h_src, a_src_al, s_src, N_A);
    // CSR build (ex precomputed at scatter)
    k_deg<<<(E + 255) / 256, 256, 0, stream>>>(edge_dst, deg, E);
    k_scanA<<<nb, 256, 0, stream>>>(deg, bsum, N_L);
    k_scanB<<<1, 128, 0, stream>>>(bsum, nb, rowptr, N_L, E);
    k_scanC<<<nb, 256, 0, stream>>>(deg, bsum, rowptr, N_L);
    k_scatter<<<(E + 255) / 256, 256, 0, stream>>>(edge_src, edge_dst, s_src, s_dst,
                                                   rowptr, cursor, csr_pair, E);
    // gather + normalize + bias + relu -> G
    k_gat<<<(N_L + 15) / 16, 256, 0, stream>>>(rowptr, csr_pair, h_src, b_al, G, N_L);
    // final GEMM
    k_out<<<2048, 256, 0, stream>>>(G, W_lin, b_lin, out, N_L);
}